// Round 17
// baseline (511.947 us; speedup 1.0000x reference)
//
#include <hip/hip_runtime.h>
#include <hip/hip_fp16.h>
#include <math.h>

// RelationMessagePassing — bf16 MFMA, fused rel kernel, CSR plain-store
// scatter (no fp16 atomics) with atomic-path fallback if ws too small.
//
// Round-16: coalescing raised the atomic-RMW rate 750->990 GB/s; payload
// (188 MB) is minimal. This round tests the RMW pipe itself: messages are
// plain-stored to a CSR msgbuf (slot = cursor int atomic, 1 per seg) with
// the same full-wave 2x128B coalescing; reduce_k sums each node's contiguous
// segment in fp32 (seeded by r0's store-only contribution). msgbuf (~179MB)
// is L3-resident. If ws_size < needed: exact round-16 atomic path (MODE 0).
//
// CSR pipeline: memset(cnt0+hist12) | conv_states | transpose_w |
//   hist_k(idx0->cnt0) hist_k(idx1,idx2->hist12) | scanA/B/C ->
//   rel_fused<1>: r0->exps_r0 stores; r1/r2->msgbuf stores | reduce_k ->
//   exps fp16 | reduce_max | up_mfma -> fp32 out.

typedef __attribute__((ext_vector_type(8))) short bf16x8;
typedef __attribute__((ext_vector_type(4))) float f32x4;
typedef __attribute__((ext_vector_type(8))) _Float16 f16x8;
typedef unsigned short u16;

__device__ __forceinline__ u16 f2bf(float f) {
    unsigned u = __float_as_uint(f);
    return (u16)((u + 0x7fffu + ((u >> 16) & 1u)) >> 16);
}

// ---------------- prep ----------------
__global__ __launch_bounds__(256) void conv_states(const float* __restrict__ src,
                                                   u16* __restrict__ dst, int n8) {
    int i = blockIdx.x * 256 + threadIdx.x;
    if (i >= n8) return;
    float4 a = reinterpret_cast<const float4*>(src)[2 * i];
    float4 b = reinterpret_cast<const float4*>(src)[2 * i + 1];
    bf16x8 v;
    v[0] = (short)f2bf(a.x); v[1] = (short)f2bf(a.y);
    v[2] = (short)f2bf(a.z); v[3] = (short)f2bf(a.w);
    v[4] = (short)f2bf(b.x); v[5] = (short)f2bf(b.y);
    v[6] = (short)f2bf(b.z); v[7] = (short)f2bf(b.w);
    reinterpret_cast<bf16x8*>(dst)[i] = v;
}

struct TEnt { const float* src; u16* dst; int K, N, base; float scale; };
struct TPack { TEnt e[8]; };
__global__ __launch_bounds__(256) void transpose_w(TPack p) {
    int b = blockIdx.x;
    int i = 0;
    while (i < 7 && b >= p.e[i + 1].base) ++i;
    TEnt e = p.e[i];
    int idx = (b - e.base) * 256 + threadIdx.x;
    if (idx < e.K * e.N) {
        int n = idx / e.K, k = idx - n * e.K;
        e.dst[idx] = f2bf(e.scale * e.src[k * e.N + n]);
    }
}

__global__ __launch_bounds__(256) void hist_k(const int* __restrict__ idx, int n,
                                              int* __restrict__ hist) {
    int i = blockIdx.x * 256 + threadIdx.x;
    if (i < n) atomicAdd(&hist[idx[i]], 1);
}

// ---------------- scan (1024/block) ----------------
__global__ __launch_bounds__(256) void scanA(const int* __restrict__ hist, int N,
                                             int* __restrict__ partial) {
    __shared__ int ts[256];
    int b = blockIdx.x, t = threadIdx.x;
    int i0 = b * 1024 + t * 4;
    int s = 0;
    #pragma unroll
    for (int q = 0; q < 4; ++q) s += (i0 + q < N) ? hist[i0 + q] : 0;
    ts[t] = s;
    __syncthreads();
    for (int off = 128; off; off >>= 1) {
        if (t < off) ts[t] += ts[t + off];
        __syncthreads();
    }
    if (t == 0) partial[b] = ts[0];
}

__global__ __launch_bounds__(256) void scanB(int* __restrict__ partial, int B1) {
    __shared__ int ts[256];
    int t = threadIdx.x;
    int v = (t < B1) ? partial[t] : 0;
    ts[t] = v;
    __syncthreads();
    for (int off = 1; off < 256; off <<= 1) {
        int x = (t >= off) ? ts[t - off] : 0;
        __syncthreads();
        ts[t] += x;
        __syncthreads();
    }
    if (t < B1) partial[t] = ts[t] - v;
}

__global__ __launch_bounds__(256) void scanC(const int* __restrict__ hist, int N,
                                             const int* __restrict__ partial,
                                             int* __restrict__ nodeStart,
                                             int* __restrict__ cursor) {
    __shared__ int ts[256];
    int b = blockIdx.x, t = threadIdx.x;
    int i0 = b * 1024 + t * 4;
    int v[4];
    int s = 0;
    #pragma unroll
    for (int q = 0; q < 4; ++q) { v[q] = (i0 + q < N) ? hist[i0 + q] : 0; s += v[q]; }
    ts[t] = s;
    __syncthreads();
    for (int off = 1; off < 256; off <<= 1) {
        int x = (t >= off) ? ts[t - off] : 0;
        __syncthreads();
        ts[t] += x;
        __syncthreads();
    }
    int run = partial[b] + ts[t] - s;
    #pragma unroll
    for (int q = 0; q < 4; ++q) {
        int i = i0 + q;
        if (i < N) {
            nodeStart[i] = run;
            cursor[i] = run;
            if (i == N - 1) nodeStart[N] = run + v[q];
            run += v[q];
        }
    }
}

// ---------------- relation bodies ----------------
// MODE: 0 = fp16 atomic scatter (round-16), 1 = CSR plain stores.
template <int D, int MODE>
__device__ __forceinline__ void rel_body(
    const u16* __restrict__ statesb, const int* __restrict__ idx,
    const u16* __restrict__ W1t, const float* __restrict__ B1,
    const u16* __restrict__ W2t, const float* __restrict__ B2,
    __half* __restrict__ exps, int* __restrict__ cursor,
    _Float16* __restrict__ msgbuf, float* __restrict__ bmslot, int E, int bid,
    u16* Xs, int* Ids, float* wmax) {
    constexpr int A = D / 64;
    constexpr int KF = D / 32;
    constexpr int NFW = D / 64;
    constexpr int CPR = D / 8;
    char* Xc = (char*)Xs;

    const int tid = threadIdx.x;
    const int block0 = bid * 64;
    const int validRows = min(64, E - block0);
    const int validSegs = validRows * A;
    const long long segBase = (long long)block0 * A;

    for (int q = tid; q < 64 * CPR; q += 256) {
        int r = q / CPR, c = q - r * CPR;
        int slot = c >> 3;
        int wc = (c & 7) ^ (r & 7);
        int seg = r * A + slot;
        bf16x8 v = {};
        if (seg < validSegs) {
            int node = idx[segBase + seg];
            v = *reinterpret_cast<const bf16x8*>(statesb + (long long)node * 64 + wc * 8);
            if ((c & 7) == 0) Ids[seg] = node;
        }
        *reinterpret_cast<bf16x8*>(Xc + q * 16) = v;
    }
    __syncthreads();

    const int l = tid & 63;
    const int ln = l & 15, kq = l >> 4;
    const int w = tid >> 6;
    const int nbase = w * NFW;

    f32x4 acc[4][NFW];
    #pragma unroll
    for (int nf = 0; nf < NFW; ++nf) {
        float b = B1[(nbase + nf) * 16 + ln];
        #pragma unroll
        for (int m = 0; m < 4; ++m) acc[m][nf] = {b, b, b, b};
    }
    #pragma unroll
    for (int kf = 0; kf < KF; ++kf) {
        bf16x8 a[4];
        #pragma unroll
        for (int m = 0; m < 4; ++m)
            a[m] = *reinterpret_cast<const bf16x8*>(
                Xc + (m * 16 + ln) * (2 * D) + ((kf * 64 + kq * 16) ^ ((ln & 7) << 4)));
        #pragma unroll
        for (int nf = 0; nf < NFW; ++nf) {
            bf16x8 b = *reinterpret_cast<const bf16x8*>(
                W1t + ((nbase + nf) * 16 + ln) * D + kf * 32 + kq * 8);
            #pragma unroll
            for (int m = 0; m < 4; ++m)
                acc[m][nf] = __builtin_amdgcn_mfma_f32_16x16x32_bf16(a[m], b, acc[m][nf], 0, 0, 0);
        }
    }
    __syncthreads();
    #pragma unroll
    for (int nf = 0; nf < NFW; ++nf) {
        const int c = (nbase + nf) * 16 + ln;
        #pragma unroll
        for (int m = 0; m < 4; ++m)
            #pragma unroll
            for (int j = 0; j < 4; ++j) {
                int row = m * 16 + kq * 4 + j;
                int byte = (c * 2) ^ ((row & 7) << 4);
                *reinterpret_cast<u16*>(Xc + row * (2 * D) + byte) =
                    f2bf(fmaxf(acc[m][nf][j], 0.f));
            }
    }
    __syncthreads();

    #pragma unroll
    for (int nf = 0; nf < NFW; ++nf) {
        float b = 8.f * B2[(nbase + nf) * 16 + ln];
        #pragma unroll
        for (int m = 0; m < 4; ++m) acc[m][nf] = {b, b, b, b};
    }
    #pragma unroll
    for (int kf = 0; kf < KF; ++kf) {
        bf16x8 a[4];
        #pragma unroll
        for (int m = 0; m < 4; ++m)
            a[m] = *reinterpret_cast<const bf16x8*>(
                Xc + (m * 16 + ln) * (2 * D) + ((kf * 64 + kq * 16) ^ ((ln & 7) << 4)));
        #pragma unroll
        for (int nf = 0; nf < NFW; ++nf) {
            bf16x8 b = *reinterpret_cast<const bf16x8*>(
                W2t + ((nbase + nf) * 16 + ln) * D + kf * 32 + kq * 8);
            #pragma unroll
            for (int m = 0; m < 4; ++m)
                acc[m][nf] = __builtin_amdgcn_mfma_f32_16x16x32_bf16(a[m], b, acc[m][nf], 0, 0, 0);
        }
    }

    float m = -INFINITY;
    #pragma unroll
    for (int mf = 0; mf < 4; ++mf)
        #pragma unroll
        for (int nf = 0; nf < NFW; ++nf)
            #pragma unroll
            for (int j = 0; j < 4; ++j) {
                int row = mf * 16 + kq * 4 + j;
                if (row < validRows) m = fmaxf(m, acc[mf][nf][j]);
            }
    #pragma unroll
    for (int off = 32; off; off >>= 1) m = fmaxf(m, __shfl_xor(m, off));
    if (l == 0) wmax[w] = m;
    __syncthreads();
    if (tid == 0)
        *bmslot = 0.125f * fmaxf(fmaxf(wmax[0], wmax[1]), fmaxf(wmax[2], wmax[3]));

    _Float16* Xh = (_Float16*)Xc;
    #pragma unroll
    for (int nf = 0; nf < NFW; ++nf) {
        const int c = (nbase + nf) * 16 + ln;
        const int slot = c >> 6;
        const int feat = c & 63;
        #pragma unroll
        for (int mf = 0; mf < 4; ++mf)
            #pragma unroll
            for (int j = 0; j < 4; ++j) {
                int row = mf * 16 + kq * 4 + j;
                Xh[(row * A + slot) * 64 + feat] = (_Float16)__expf(acc[mf][nf][j]);
            }
    }
    __syncthreads();

    {
        constexpr int SPW = 16 * A;
        const int fp = l & 31;
        for (int s0 = w * SPW; s0 < (w + 1) * SPW; s0 += 2) {
            int seg = s0 + (l >> 5);
            if (MODE == 0) {
                if (seg < validSegs) {
                    int node = Ids[seg];
                    __half2 pk = *reinterpret_cast<const __half2*>(Xc + seg * 128 + fp * 4);
                    unsafeAtomicAdd(reinterpret_cast<__half2*>(
                        exps + (long long)node * 64 + fp * 2), pk);
                }
            } else {
                int pos = 0;
                if (seg < validSegs && (l & 31) == 0)
                    pos = atomicAdd(&cursor[Ids[seg]], 1);
                pos = __shfl(pos, l & 32);      // broadcast from lane 0 / lane 32
                if (seg < validSegs) {
                    __half2 pk = *reinterpret_cast<const __half2*>(Xc + seg * 128 + fp * 4);
                    *reinterpret_cast<__half2*>((__half*)msgbuf +
                        (long long)pos * 64 + fp * 2) = pk;
                }
            }
        }
    }
}

// Arity-1 dedup body. MODE 0: atomic into exps; MODE 1: plain store exps_r0.
template <int MODE>
__device__ __forceinline__ void rel0_body(
    const u16* __restrict__ statesb, const int* __restrict__ cnt,
    const u16* __restrict__ W1t, const float* __restrict__ B1,
    const u16* __restrict__ W2t, const float* __restrict__ B2,
    __half* __restrict__ exps, _Float16* __restrict__ r0v,
    float* __restrict__ bmslot, int Nn, int bid, u16* Xs, float* wmax) {
    constexpr int D = 64, KF = 2, CPR = 8;
    char* Xc = (char*)Xs;
    const int tid = threadIdx.x;
    const int block0 = bid * 64;
    const int validRows = min(64, Nn - block0);

    for (int q = tid; q < 64 * CPR; q += 256) {
        int r = q / CPR, c = q - r * CPR;
        int wc = (c & 7) ^ (r & 7);
        bf16x8 v = {};
        if (r < validRows)
            v = *reinterpret_cast<const bf16x8*>(
                statesb + (long long)(block0 + r) * 64 + wc * 8);
        *reinterpret_cast<bf16x8*>(Xc + q * 16) = v;
    }
    __syncthreads();

    const int l = tid & 63;
    const int ln = l & 15, kq = l >> 4;
    const int w = tid >> 6;

    f32x4 acc[4];
    {
        float b = B1[w * 16 + ln];
        #pragma unroll
        for (int m = 0; m < 4; ++m) acc[m] = {b, b, b, b};
    }
    #pragma unroll
    for (int kf = 0; kf < KF; ++kf) {
        bf16x8 a[4];
        #pragma unroll
        for (int m = 0; m < 4; ++m)
            a[m] = *reinterpret_cast<const bf16x8*>(
                Xc + (m * 16 + ln) * (2 * D) + ((kf * 64 + kq * 16) ^ ((ln & 7) << 4)));
        bf16x8 b = *reinterpret_cast<const bf16x8*>(
            W1t + (w * 16 + ln) * D + kf * 32 + kq * 8);
        #pragma unroll
        for (int m = 0; m < 4; ++m)
            acc[m] = __builtin_amdgcn_mfma_f32_16x16x32_bf16(a[m], b, acc[m], 0, 0, 0);
    }
    __syncthreads();
    #pragma unroll
    for (int m = 0; m < 4; ++m)
        #pragma unroll
        for (int j = 0; j < 4; ++j) {
            int row = m * 16 + kq * 4 + j;
            int byte = ((w * 16 + ln) * 2) ^ ((row & 7) << 4);
            *reinterpret_cast<u16*>(Xc + row * (2 * D) + byte) =
                f2bf(fmaxf(acc[m][j], 0.f));
        }
    __syncthreads();
    {
        float b = 8.f * B2[w * 16 + ln];
        #pragma unroll
        for (int m = 0; m < 4; ++m) acc[m] = {b, b, b, b};
    }
    #pragma unroll
    for (int kf = 0; kf < KF; ++kf) {
        bf16x8 a[4];
        #pragma unroll
        for (int m = 0; m < 4; ++m)
            a[m] = *reinterpret_cast<const bf16x8*>(
                Xc + (m * 16 + ln) * (2 * D) + ((kf * 64 + kq * 16) ^ ((ln & 7) << 4)));
        bf16x8 b = *reinterpret_cast<const bf16x8*>(
            W2t + (w * 16 + ln) * D + kf * 32 + kq * 8);
        #pragma unroll
        for (int m = 0; m < 4; ++m)
            acc[m] = __builtin_amdgcn_mfma_f32_16x16x32_bf16(a[m], b, acc[m], 0, 0, 0);
    }

    float m = -INFINITY;
    int cn[4][4];
    #pragma unroll
    for (int mf = 0; mf < 4; ++mf)
        #pragma unroll
        for (int j = 0; j < 4; ++j) {
            int row = mf * 16 + kq * 4 + j;
            cn[mf][j] = (row < validRows) ? cnt[block0 + row] : 0;
            if (cn[mf][j] > 0) m = fmaxf(m, acc[mf][j]);
        }
    #pragma unroll
    for (int off = 32; off; off >>= 1) m = fmaxf(m, __shfl_xor(m, off));
    if (l == 0) wmax[w] = m;
    __syncthreads();
    if (tid == 0)
        *bmslot = 0.125f * fmaxf(fmaxf(wmax[0], wmax[1]), fmaxf(wmax[2], wmax[3]));

    _Float16* Xh = (_Float16*)Xc;
    const int feat = w * 16 + ln;
    #pragma unroll
    for (int mf = 0; mf < 4; ++mf)
        #pragma unroll
        for (int j = 0; j < 4; ++j) {
            int row = mf * 16 + kq * 4 + j;
            Xh[row * 64 + feat] = (_Float16)((float)cn[mf][j] * __expf(acc[mf][j]));
        }
    __syncthreads();

    {
        const int fp = l & 31;
        for (int s0 = w * 16; s0 < (w + 1) * 16; s0 += 2) {
            int row = s0 + (l >> 5);
            if (row >= validRows) continue;
            __half2 pk = *reinterpret_cast<const __half2*>(Xc + row * 128 + fp * 4);
            if (MODE == 0) {
                if (cnt[block0 + row] > 0)
                    unsafeAtomicAdd(reinterpret_cast<__half2*>(
                        exps + (long long)(block0 + row) * 64 + fp * 2), pk);
            } else {
                *reinterpret_cast<__half2*>((__half*)r0v +
                    (long long)(block0 + row) * 64 + fp * 2) = pk;
            }
        }
    }
}

struct RelArgs {
    const u16* statesb;
    const int* cnt0; const int* idx1; const int* idx2;
    const u16* w1t0; const float* b10; const u16* w2t0; const float* b20;
    const u16* w1t1; const float* b11; const u16* w2t1; const float* b21;
    const u16* w1t2; const float* b12; const u16* w2t2; const float* b22;
    __half* exps;
    int* cursor;
    _Float16* msgbuf;
    _Float16* r0v;
    float* blockmax;
    int Nn, E1, E2, G0, G01;
};

template <int MODE>
__global__ __launch_bounds__(256) void rel_fused(RelArgs a) {
    __shared__ __align__(16) u16 Xs[64 * 192];
    __shared__ int Ids[64 * 3];
    __shared__ float wmax[4];
    const int bid = blockIdx.x;
    if (bid < a.G0)
        rel0_body<MODE>(a.statesb, a.cnt0, a.w1t0, a.b10, a.w2t0, a.b20,
                        a.exps, a.r0v, a.blockmax + bid, a.Nn, bid, Xs, wmax);
    else if (bid < a.G01)
        rel_body<128, MODE>(a.statesb, a.idx1, a.w1t1, a.b11, a.w2t1, a.b21,
                            a.exps, a.cursor, a.msgbuf, a.blockmax + bid,
                            a.E1, bid - a.G0, Xs, Ids, wmax);
    else
        rel_body<192, MODE>(a.statesb, a.idx2, a.w1t2, a.b12, a.w2t2, a.b22,
                            a.exps, a.cursor, a.msgbuf, a.blockmax + bid,
                            a.E2, bid - a.G01, Xs, Ids, wmax);
}

// ---------------- segment reduce (CSR mode) ----------------
__global__ __launch_bounds__(256) void reduce_k(const _Float16* __restrict__ msgbuf,
                                                const int* __restrict__ nodeStart,
                                                const _Float16* __restrict__ r0v,
                                                __half* __restrict__ exps, int Nn) {
    int node = (blockIdx.x * 256 + threadIdx.x) >> 6;
    if (node >= Nn) return;
    int lane = threadIdx.x & 63;
    int s = nodeStart[node], e = nodeStart[node + 1];
    float S = (float)r0v[(long long)node * 64 + lane];
    for (int i = s; i < e; ++i) S += (float)msgbuf[(long long)i * 64 + lane];
    exps[(long long)node * 64 + lane] = __float2half(S);
}

// ---------------- global max over block maxima ----------------
__global__ __launch_bounds__(256) void reduce_max(const float* __restrict__ bm,
                                                  int n, float* __restrict__ out) {
    __shared__ float ws_[4];
    float m = -INFINITY;
    for (int i = threadIdx.x; i < n; i += 256) m = fmaxf(m, bm[i]);
    #pragma unroll
    for (int off = 32; off; off >>= 1) m = fmaxf(m, __shfl_xor(m, off));
    if ((threadIdx.x & 63) == 0) ws_[threadIdx.x >> 6] = m;
    __syncthreads();
    if (threadIdx.x == 0)
        out[0] = fmaxf(fmaxf(ws_[0], ws_[1]), fmaxf(ws_[2], ws_[3]));
}

// ---------------- up kernel ----------------
__global__ __launch_bounds__(256) void up_mfma(
    const u16* __restrict__ statesb, const _Float16* __restrict__ exps,
    const float* __restrict__ gmaxp,
    const u16* __restrict__ W1t, const float* __restrict__ B1,
    const u16* __restrict__ W2t, const float* __restrict__ B2,
    float* __restrict__ outp, int Nn) {
    constexpr int D = 128;
    __shared__ __align__(16) u16 Xs[64 * D];
    char* Xc = (char*)Xs;
    const int tid = threadIdx.x;
    const int block0 = blockIdx.x * 64;
    const int validRows = min(64, Nn - block0);
    const float M = gmaxp[0];
    const float EM = __expf(-8.f * M);

    for (int q = tid; q < 64 * 16; q += 256) {
        int r = q >> 4, p = q & 15;
        bf16x8 v = {};
        if (r < validRows) {
            long long nd = block0 + r;
            if (p < 8) {
                f16x8 s = *reinterpret_cast<const f16x8*>(exps + nd * 64 + p * 8);
                #pragma unroll
                for (int i = 0; i < 8; ++i)
                    v[i] = (short)f2bf(__logf(1e-16f + (float)s[i] * EM) * 0.125f + M);
            } else {
                v = *reinterpret_cast<const bf16x8*>(statesb + nd * 64 + (p - 8) * 8);
            }
        }
        int byte = (p * 16) ^ ((r & 7) << 4);
        *reinterpret_cast<bf16x8*>(Xc + r * 256 + byte) = v;
    }
    __syncthreads();

    const int l = tid & 63;
    const int ln = l & 15, kq = l >> 4;
    const int row0 = (tid >> 6) * 16;

    f32x4 acc[8];
    #pragma unroll
    for (int n = 0; n < 8; ++n) {
        float b = B1[n * 16 + ln];
        acc[n] = {b, b, b, b};
    }
    {
        const u16* wb = W1t + ln * D + kq * 8;
        #pragma unroll
        for (int kf = 0; kf < 4; ++kf) {
            bf16x8 a = *reinterpret_cast<const bf16x8*>(
                Xc + (row0 + ln) * 256 + ((kf * 64 + kq * 16) ^ ((ln & 7) << 4)));
            #pragma unroll
            for (int n = 0; n < 8; ++n) {
                bf16x8 b = *reinterpret_cast<const bf16x8*>(wb + n * 16 * D + kf * 32);
                acc[n] = __builtin_amdgcn_mfma_f32_16x16x32_bf16(a, b, acc[n], 0, 0, 0);
            }
        }
    }
    #pragma unroll
    for (int n = 0; n < 8; ++n) {
        #pragma unroll
        for (int j = 0; j < 4; ++j) {
            int rl = kq * 4 + j;
            int byte = ((n * 16 + ln) * 2) ^ ((rl & 7) << 4);
            *reinterpret_cast<u16*>(Xc + (row0 + rl) * 256 + byte) =
                f2bf(fmaxf(acc[n][j], 0.f));
        }
    }
    f32x4 acc2[4];
    #pragma unroll
    for (int n = 0; n < 4; ++n) {
        float b = B2[n * 16 + ln];
        acc2[n] = {b, b, b, b};
    }
    {
        const u16* wb = W2t + ln * D + kq * 8;
        #pragma unroll
        for (int kf = 0; kf < 4; ++kf) {
            bf16x8 a = *reinterpret_cast<const bf16x8*>(
                Xc + (row0 + ln) * 256 + ((kf * 64 + kq * 16) ^ ((ln & 7) << 4)));
            #pragma unroll
            for (int n = 0; n < 4; ++n) {
                bf16x8 b = *reinterpret_cast<const bf16x8*>(wb + n * 16 * D + kf * 32);
                acc2[n] = __builtin_amdgcn_mfma_f32_16x16x32_bf16(a, b, acc2[n], 0, 0, 0);
            }
        }
    }
    #pragma unroll
    for (int n = 0; n < 4; ++n)
        #pragma unroll
        for (int j = 0; j < 4; ++j) {
            int row = row0 + kq * 4 + j;
            if (row < validRows)
                outp[(long long)(block0 + row) * 64 + n * 16 + ln] = acc2[n][j];
        }
}

extern "C" void kernel_launch(void* const* d_in, const int* in_sizes, int n_in,
                              void* d_out, int out_size, void* d_ws, size_t ws_size,
                              hipStream_t stream) {
    const float* states = (const float*)d_in[0];
    const int* idxp[3] = {(const int*)d_in[1], (const int*)d_in[2], (const int*)d_in[3]};
    const float* rw1[3] = {(const float*)d_in[4], (const float*)d_in[8], (const float*)d_in[12]};
    const float* rb1[3] = {(const float*)d_in[5], (const float*)d_in[9], (const float*)d_in[13]};
    const float* rw2[3] = {(const float*)d_in[6], (const float*)d_in[10], (const float*)d_in[14]};
    const float* rb2[3] = {(const float*)d_in[7], (const float*)d_in[11], (const float*)d_in[15]};
    const float* upw1 = (const float*)d_in[16];
    const float* upb1 = (const float*)d_in[17];
    const float* upw2 = (const float*)d_in[18];
    const float* upb2 = (const float*)d_in[19];

    const int N = in_sizes[0] / 64;
    const int L0 = in_sizes[1], L1 = in_sizes[2], L2 = in_sizes[3];
    const int E1 = L1 / 2, E2 = L2 / 3;
    const long long P12 = (long long)L1 + L2;
    const int G0 = (N + 63) / 64;
    const int G1 = (E1 + 63) / 64, G2 = (E2 + 63) / 64;
    const int Gtot = G0 + G1 + G2;
    const int Dd[3] = {64, 128, 192};
    const int B1n = (N + 1023) / 1024;

    size_t off = 0;
    auto alloc = [&](size_t bytes) {
        void* p = (char*)d_ws + off;
        off += (bytes + 255) & ~(size_t)255;
        return p;
    };
    float* gmaxf = (float*)alloc(4);
    float* blockmax = (float*)alloc((size_t)Gtot * 4);
    __half* exps = (__half*)alloc((size_t)N * 64 * 2);
    int* cnt0 = (int*)alloc((size_t)N * 4);
    int* hist12 = (int*)alloc((size_t)N * 4);
    int* nodeStart = (int*)alloc((size_t)(N + 1) * 4);
    int* partial = (int*)alloc(4096);
    int* cursor = (int*)alloc((size_t)N * 4);
    _Float16* r0v = (_Float16*)alloc((size_t)N * 64 * 2);
    u16* statesb = (u16*)alloc((size_t)N * 64 * 2);
    u16* w1t[3], *w2t[3];
    for (int r = 0; r < 3; ++r) {
        w1t[r] = (u16*)alloc((size_t)Dd[r] * Dd[r] * 2);
        w2t[r] = (u16*)alloc((size_t)Dd[r] * Dd[r] * 2);
    }
    u16* upw1t = (u16*)alloc(128 * 128 * 2);
    u16* upw2t = (u16*)alloc(64 * 128 * 2);
    _Float16* msgbuf = (_Float16*)alloc((size_t)P12 * 64 * 2);
    const bool csr = (off <= ws_size);

    conv_states<<<dim3((N * 64 / 8 + 255) / 256), dim3(256), 0, stream>>>(
        states, statesb, N * 64 / 8);

    TPack tp;
    const float* tsrc[8] = {rw1[0], rw2[0], rw1[1], rw2[1], rw1[2], rw2[2], upw1, upw2};
    u16* tdst[8] = {w1t[0], w2t[0], w1t[1], w2t[1], w1t[2], w2t[2], upw1t, upw2t};
    const int tK[8] = {64, 64, 128, 128, 192, 192, 128, 128};
    const int tN[8] = {64, 64, 128, 128, 192, 192, 128, 64};
    const float tsc[8] = {1.f, 8.f, 1.f, 8.f, 1.f, 8.f, 1.f, 1.f};
    int base = 0;
    for (int i = 0; i < 8; ++i) {
        tp.e[i] = {tsrc[i], tdst[i], tK[i], tN[i], base, tsc[i]};
        base += (tK[i] * tN[i] + 255) / 256;
    }
    transpose_w<<<dim3(base), dim3(256), 0, stream>>>(tp);

    RelArgs ra;
    ra.statesb = statesb;
    ra.cnt0 = cnt0; ra.idx1 = idxp[1]; ra.idx2 = idxp[2];
    ra.w1t0 = w1t[0]; ra.b10 = rb1[0]; ra.w2t0 = w2t[0]; ra.b20 = rb2[0];
    ra.w1t1 = w1t[1]; ra.b11 = rb1[1]; ra.w2t1 = w2t[1]; ra.b21 = rb2[1];
    ra.w1t2 = w1t[2]; ra.b12 = rb1[2]; ra.w2t2 = w2t[2]; ra.b22 = rb2[2];
    ra.exps = exps;
    ra.cursor = cursor;
    ra.msgbuf = msgbuf;
    ra.r0v = r0v;
    ra.blockmax = blockmax;
    ra.Nn = N; ra.E1 = E1; ra.E2 = E2; ra.G0 = G0; ra.G01 = G0 + G1;

    if (csr) {
        // zero cnt0 + hist12 (contiguous)
        size_t zoff = (char*)cnt0 - (char*)d_ws;
        size_t zlen = ((char*)hist12 - (char*)cnt0) + (size_t)N * 4;
        (void)hipMemsetAsync((char*)d_ws + zoff, 0, zlen, stream);
        hist_k<<<dim3((L0 + 255) / 256), dim3(256), 0, stream>>>(idxp[0], L0, cnt0);
        hist_k<<<dim3((L1 + 255) / 256), dim3(256), 0, stream>>>(idxp[1], L1, hist12);
        hist_k<<<dim3((L2 + 255) / 256), dim3(256), 0, stream>>>(idxp[2], L2, hist12);
        scanA<<<dim3(B1n), dim3(256), 0, stream>>>(hist12, N, partial);
        scanB<<<dim3(1), dim3(256), 0, stream>>>(partial, B1n);
        scanC<<<dim3(B1n), dim3(256), 0, stream>>>(hist12, N, partial, nodeStart, cursor);
        rel_fused<1><<<dim3(Gtot), dim3(256), 0, stream>>>(ra);
        reduce_k<<<dim3(((size_t)N * 64 + 255) / 256), dim3(256), 0, stream>>>(
            msgbuf, nodeStart, r0v, exps, N);
    } else {
        // fallback: round-16 atomic path (zero exps + cnt0)
        size_t zoff = (char*)exps - (char*)d_ws;
        size_t zlen = ((char*)cnt0 - (char*)exps) + (size_t)N * 4;
        (void)hipMemsetAsync((char*)d_ws + zoff, 0, zlen, stream);
        hist_k<<<dim3((L0 + 255) / 256), dim3(256), 0, stream>>>(idxp[0], L0, cnt0);
        rel_fused<0><<<dim3(Gtot), dim3(256), 0, stream>>>(ra);
    }

    reduce_max<<<dim3(1), dim3(256), 0, stream>>>(blockmax, Gtot, gmaxf);

    up_mfma<<<dim3((N + 63) / 64), dim3(256), 0, stream>>>(
        statesb, (const _Float16*)exps, gmaxf, upw1t, upb1, upw2t, upb2,
        (float*)d_out, N);
}